// Round 10
// baseline (231.452 us; speedup 1.0000x reference)
//
#include <hip/hip_runtime.h>

#define T_SEQ 4096
#define NBATCH 4
#define CDIM 1024
#define NHEAD 64
#define SCALE (1.0f / 32.0f)
#define LOG2E 1.4426950408889634f
#define BT (NBATCH * T_SEQ)
#define NW 8             // waves per attn block (key-split factor)
#define WREG 8960        // per-wave LDS region bytes
#define PSTR 9           // P-tile row stride in u64: 8 data slots + 1 pad
#define THR2 11.0f       // defer-max threshold in log2 domain (~8 nats)

typedef __bf16 bf16x8 __attribute__((ext_vector_type(8)));
typedef float f32x4 __attribute__((ext_vector_type(4)));
typedef unsigned long long u64;

__device__ __forceinline__ unsigned short f2bf(float f) {
  union { float f; unsigned u; } x;
  x.f = f;
  unsigned r = x.u + 0x7FFFu + ((x.u >> 16) & 1u);
  return (unsigned short)(r >> 16);
}

// RNE pack of two f32 -> one u32 of 2 bf16 (same rounding as f2bf)
__device__ __forceinline__ unsigned cvt_pk(float lo, float hi) {
  unsigned d;
  asm("v_cvt_pk_bf16_f32 %0, %1, %2" : "=v"(d) : "v"(lo), "v"(hi));
  return d;
}

__device__ __forceinline__ f32x4 mfma16(bf16x8 a, bf16x8 b, f32x4 c) {
  return __builtin_amdgcn_mfma_f32_16x16x32_bf16(a, b, c, 0, 0, 0);
}

__device__ __forceinline__ bf16x8 ones8() {
  bf16x8 v;
  for (int j = 0; j < 8; ++j) v[j] = (__bf16)1.0f;
  return v;
}

// ---------------------------------------------------------------------------
// Kernel 1: Wt[c][k] = W*(k, c%64) * (c<64 ? SCALE*log2e : 1), bf16.
// Q pre-scaled into the log2 domain so attn's softmax uses raw exp2 (single
// v_exp_f32, no mul) and the max/merge bookkeeping stays in log2 units.
// ---------------------------------------------------------------------------
__global__ void prep_w(const float* __restrict__ Wq, const float* __restrict__ Wk,
                       const float* __restrict__ Wv, unsigned short* __restrict__ Wt) {
  int c = blockIdx.x;
  const float* W = (c < 64) ? Wq : (c < 128) ? Wk : Wv;
  int cc = c & 63;
  float sc = (c < 64) ? (SCALE * LOG2E) : 1.0f;
  for (int k = threadIdx.x; k < CDIM; k += blockDim.x)
    Wt[c * CDIM + k] = f2bf(W[k * NHEAD + cc] * sc);
}

// ---------------------------------------------------------------------------
// Kernel 2: fused QKV projection, BK=128 with register prefetch.
// M-tile = 32 rows, 512 blocks x 4 waves -> 2 blocks/CU.
// Writes q,k row-major [BT][64] bf16; v transposed [64][BT] bf16.
// ---------------------------------------------------------------------------
__global__ __launch_bounds__(256) void proj_qkv(
    const float* __restrict__ x, const unsigned short* __restrict__ Wt,
    unsigned short* __restrict__ qws, unsigned short* __restrict__ kws,
    unsigned short* __restrict__ vtws) {
  __shared__ unsigned short xlds[32][136];  // 128 bf16 + 8 pad
  const int tid = threadIdx.x;
  const int lane = tid & 63;
  const int w = tid >> 6;
  const int g = lane >> 4;
  const int c15 = lane & 15;
  const int rb = blockIdx.x * 32;

  f32x4 acc[2][3];
  for (int i = 0; i < 2; i++)
    for (int j = 0; j < 3; j++) acc[i][j] = (f32x4){0.f, 0.f, 0.f, 0.f};

  const int sr = tid >> 3;         // staging row 0..31
  const int scc = (tid & 7) * 16;  // staging col base (floats)
  const float* xrow = x + (size_t)(rb + sr) * CDIM + scc;

  float4 cur[4];
  for (int i = 0; i < 4; i++) cur[i] = *(const float4*)(xrow + i * 4);

  for (int k0 = 0; k0 < CDIM; k0 += 128) {
    unsigned short pk[16];
    for (int i = 0; i < 4; i++) {
      pk[i * 4 + 0] = f2bf(cur[i].x);
      pk[i * 4 + 1] = f2bf(cur[i].y);
      pk[i * 4 + 2] = f2bf(cur[i].z);
      pk[i * 4 + 3] = f2bf(cur[i].w);
    }
    *(bf16x8*)&xlds[sr][scc] = *(bf16x8*)&pk[0];
    *(bf16x8*)&xlds[sr][scc + 8] = *(bf16x8*)&pk[8];
    __syncthreads();
    if (k0 + 128 < CDIM)
      for (int i = 0; i < 4; i++)
        cur[i] = *(const float4*)(xrow + k0 + 128 + i * 4);

    for (int kk = 0; kk < 4; kk++) {
      bf16x8 a[2];
      for (int mt = 0; mt < 2; mt++)
        a[mt] = *(bf16x8*)&xlds[mt * 16 + c15][kk * 32 + g * 8];
      for (int bn = 0; bn < 3; bn++) {
        int col = w * 48 + bn * 16 + c15;
        bf16x8 bfrag =
            *(const bf16x8*)&Wt[(size_t)col * CDIM + k0 + kk * 32 + g * 8];
        for (int mt = 0; mt < 2; mt++)
          acc[mt][bn] = mfma16(a[mt], bfrag, acc[mt][bn]);
      }
    }
    __syncthreads();
  }

  for (int mt = 0; mt < 2; mt++)
    for (int bn = 0; bn < 3; bn++) {
      int col = w * 48 + bn * 16 + c15;
      int row0 = rb + mt * 16 + 4 * g;
      for (int r = 0; r < 4; r++) {
        unsigned short v = f2bf(acc[mt][bn][r]);
        int t = row0 + r;
        if (col < 64)
          qws[(size_t)t * 64 + col] = v;
        else if (col < 128)
          kws[(size_t)t * 64 + (col - 64)] = v;
        else
          vtws[(size_t)(col - 128) * BT + t] = v;
      }
    }
}

// ---------------------------------------------------------------------------
// Kernel 3: causal flash attention. R9 diagnosis: ~6500 cy/step, ~490 VALU
// instr/step/wave, dependent-chain latency-bound. This round: VALU diet
// (cvt_pk packing ~190->12 ops, exp2 domain removes 16 muls, ping-pong
// unroll kills 64 rotate-movs) + 2 blocks/CU (512 blocks x 1 q-tile each,
// pair-ordered so co-resident blocks balance; launch_bounds(512,4) caps regs
// at 128, measured demand 112).
// S = mfma(K,Q) with Q pre-scaled by SCALE*log2e: lane c = q-row, keys on
// 4g+r. P = exp2(sv - m2); l via ones-MFMA; defer-max THR2=11 (log2).
// P tile per-wave LDS, u64-only, PSTR=9 -> 0 bank conflicts (R8/R9 measured).
// Per-wave WREG 8960 B: P [32][9] u64 in loop; o[32][68] f32 @0, m @8704,
// l @8832 after.
// ---------------------------------------------------------------------------
__global__ __launch_bounds__(512, 4) void attn_fwd(
    const unsigned short* __restrict__ qws, const unsigned short* __restrict__ kws,
    const unsigned short* __restrict__ vtws, float* __restrict__ out) {
  __shared__ __align__(16) char smem[NW * WREG];  // 70 KiB -> 2 blocks/CU
  const int tid = threadIdx.x;
  const int lane = tid & 63;
  const int w = tid >> 6;
  const int g = lane >> 4;
  const int c = lane & 15;
  const int b = blockIdx.x >> 7;
  const int j = blockIdx.x & 127;
  const int qt = (j & 1) ? (127 - (j >> 1)) : (j >> 1);  // pair-balanced order
  const int qb = qt * 32;
  const int nsteps = qt + 1;
  const size_t rowbase = (size_t)b * T_SEQ;
  char* wbase = smem + w * WREG;
  u64* pl = (u64*)wbase;  // P tile: row stride PSTR u64
  const bf16x8 vone = ones8();

  bf16x8 qf[2][2];
  for (int mi = 0; mi < 2; mi++)
    for (int hc = 0; hc < 2; hc++)
      qf[mi][hc] = *(const bf16x8*)&qws[(rowbase + qb + mi * 16 + c) * 64 +
                                        hc * 32 + g * 8];

  f32x4 o[2][4];
  f32x4 o5[2];
  float mrow[2];
  for (int mi = 0; mi < 2; mi++) {
    for (int nt = 0; nt < 4; nt++) o[mi][nt] = (f32x4){0.f, 0.f, 0.f, 0.f};
    o5[mi] = (f32x4){0.f, 0.f, 0.f, 0.f};
    mrow[mi] = -1e30f;
  }

  auto PREF = [&](int st, bf16x8 (&k0)[2], bf16x8 (&k1)[2], bf16x8 (&v)[4]) {
    const int kt = st * 32;
    for (int kn = 0; kn < 2; kn++) {
      k0[kn] = *(const bf16x8*)&kws[(rowbase + kt + kn * 16 + c) * 64 + g * 8];
      k1[kn] =
          *(const bf16x8*)&kws[(rowbase + kt + kn * 16 + c) * 64 + 32 + g * 8];
    }
    for (int nt = 0; nt < 4; nt++)
      v[nt] =
          *(const bf16x8*)&vtws[(size_t)(nt * 16 + c) * BT + rowbase + kt + g * 8];
  };

  auto COMPUTE = [&](int st, bf16x8 (&k0)[2], bf16x8 (&k1)[2], bf16x8 (&v)[4]) {
    const int kt = st * 32;
    // S = mfma(K, Q): lane c = q-row, reg r = key 4g+r (+16 kn); log2 units
    f32x4 sv[2][2];
    for (int mi = 0; mi < 2; mi++)
      for (int kn = 0; kn < 2; kn++) {
        f32x4 z = (f32x4){0.f, 0.f, 0.f, 0.f};
        z = mfma16(k0[kn], qf[mi][0], z);
        sv[mi][kn] = mfma16(k1[kn], qf[mi][1], z);
      }

    if (st == nsteps - 1) {  // diagonal tile: causal mask
      for (int mi = 0; mi < 2; mi++)
        for (int kn = 0; kn < 2; kn++)
          for (int r = 0; r < 4; r++) {
            int key = kt + kn * 16 + 4 * g + r;
            int qr = qb + mi * 16 + c;
            if (key > qr) sv[mi][kn][r] = -1e30f;
          }
    }

    for (int mi = 0; mi < 2; mi++) {
      float t = fmaxf(
          fmaxf(fmaxf(sv[mi][0][0], sv[mi][0][1]),
                fmaxf(sv[mi][0][2], sv[mi][0][3])),
          fmaxf(fmaxf(sv[mi][1][0], sv[mi][1][1]),
                fmaxf(sv[mi][1][2], sv[mi][1][3])));
      t = fmaxf(t, __shfl_xor(t, 16));
      t = fmaxf(t, __shfl_xor(t, 32));
      if (__any(t > mrow[mi] + THR2)) {  // defer-max (log2 domain)
        float mn = fmaxf(mrow[mi], t);
        float a = exp2f(mrow[mi] - mn);
        mrow[mi] = mn;
        for (int nt = 0; nt < 4; nt++) o[mi][nt] *= a;
        o5[mi] *= a;
      }
      float p[8];
      for (int kn = 0; kn < 2; kn++)
        for (int r = 0; r < 4; r++)
          p[kn * 4 + r] = exp2f(sv[mi][kn][r] - mrow[mi]);
      unsigned d0 = cvt_pk(p[0], p[1]);
      unsigned d1 = cvt_pk(p[2], p[3]);
      unsigned d2 = cvt_pk(p[4], p[5]);
      unsigned d3 = cvt_pk(p[6], p[7]);
      int row = mi * 16 + c;
      pl[row * PSTR + g] = ((u64)d1 << 32) | d0;      // slots 0..3: keys 4g..4g+3
      pl[row * PSTR + 4 + g] = ((u64)d3 << 32) | d2;  // slots 4..7: keys 16+4g..
    }

    asm volatile("" ::: "memory");  // pin P stores before PV loads

    // PV: O = mfma(V, P); l = mfma(1, P). Lane c = q-row for both.
    for (int mi = 0; mi < 2; mi++) {
      union { u64 q[2]; bf16x8 v8; } pu;
      pu.q[0] = pl[(mi * 16 + c) * PSTR + 2 * g];      // keys 8g..8g+3
      pu.q[1] = pl[(mi * 16 + c) * PSTR + 2 * g + 1];  // keys 8g+4..8g+7
      bf16x8 pa = pu.v8;
      for (int nt = 0; nt < 4; nt++)
        o[mi][nt] = mfma16(v[nt], pa, o[mi][nt]);
      o5[mi] = mfma16(vone, pa, o5[mi]);
    }
  };

  // ping-pong double buffer (no rotate movs)
  bf16x8 ka0[2], ka1[2], va[4], kb0[2], kb1[2], vb[4];
  if (w < nsteps) PREF(w, ka0, ka1, va);
  int st = w;
  while (st < nsteps) {
    if (st + NW < nsteps) PREF(st + NW, kb0, kb1, vb);
    COMPUTE(st, ka0, ka1, va);
    st += NW;
    if (st >= nsteps) break;
    if (st + NW < nsteps) PREF(st + NW, ka0, ka1, va);
    COMPUTE(st, kb0, kb1, vb);
    st += NW;
  }

  // ---- per-wave partials (P region dead now); o stride 68 f32 ----
  float* ow = (float*)wbase;
  float* mw = (float*)(wbase + 8704);
  float* lw = (float*)(wbase + 8832);
  for (int mi = 0; mi < 2; mi++)
    for (int nt = 0; nt < 4; nt++)
      for (int r = 0; r < 4; r++)
        ow[(mi * 16 + c) * 68 + nt * 16 + 4 * g + r] = o[mi][nt][r];
  if (g == 0)
    for (int mi = 0; mi < 2; mi++) {
      mw[mi * 16 + c] = mrow[mi];
      lw[mi * 16 + c] = o5[mi][0];
    }
  __syncthreads();

  // ---- LSE-merge across 8 waves (log2 domain): 512 thr x 4 = 32x64 ----
  for (int i = 0; i < 4; i++) {
    int e = tid + i * 512;
    int row = e >> 6;
    int d = e & 63;
    float M = -1e30f;
    for (int ww = 0; ww < NW; ww++)
      M = fmaxf(M, ((const float*)(smem + ww * WREG + 8704))[row]);
    float L = 0.f, O = 0.f;
    for (int ww = 0; ww < NW; ww++) {
      float mv = ((const float*)(smem + ww * WREG + 8704))[row];
      float f = exp2f(mv - M);
      L += f * ((const float*)(smem + ww * WREG + 8832))[row];
      O += f * ((const float*)(smem + ww * WREG))[row * 68 + d];
    }
    out[(rowbase + qb + row) * 64 + d] = O / L;
  }
}

// ---------------------------------------------------------------------------
extern "C" void kernel_launch(void* const* d_in, const int* in_sizes, int n_in,
                              void* d_out, int out_size, void* d_ws, size_t ws_size,
                              hipStream_t stream) {
  const float* x = (const float*)d_in[0];
  const float* Wq = (const float*)d_in[1];
  const float* Wk = (const float*)d_in[2];
  const float* Wv = (const float*)d_in[3];
  float* out = (float*)d_out;

  char* ws = (char*)d_ws;
  unsigned short* Wt = (unsigned short*)(ws);                          // 384 KB
  unsigned short* qws = (unsigned short*)(ws + 393216);                // 2 MB
  unsigned short* kws = (unsigned short*)(ws + 393216 + 2097152);      // 2 MB
  unsigned short* vtws = (unsigned short*)(ws + 393216 + 2 * 2097152); // 2 MB

  prep_w<<<dim3(192), dim3(256), 0, stream>>>(Wq, Wk, Wv, Wt);
  proj_qkv<<<dim3(512), dim3(256), 0, stream>>>(x, Wt, qws, kws, vtws);
  attn_fwd<<<dim3(512), dim3(512), 0, stream>>>(qws, kws, vtws, out);
}

// Round 11
// 85.240 us; speedup vs baseline: 2.7153x; 2.7153x over previous
//
#include <hip/hip_runtime.h>

#define T_SEQ 4096
#define NBATCH 4
#define CDIM 1024
#define NHEAD 64
#define SCALE (1.0f / 32.0f)
#define LOG2E 1.4426950408889634f
#define BT (NBATCH * T_SEQ)
#define NW 8             // waves per attn block (key-split factor)
#define WREG 8960        // per-wave LDS region bytes
#define PSTR 9           // P-tile row stride in u64: 8 data slots + 1 pad
#define THR2 11.0f       // defer-max threshold in log2 domain (~8 nats)

typedef __bf16 bf16x8 __attribute__((ext_vector_type(8)));
typedef float f32x4 __attribute__((ext_vector_type(4)));
typedef unsigned long long u64;

__device__ __forceinline__ unsigned short f2bf(float f) {
  union { float f; unsigned u; } x;
  x.f = f;
  unsigned r = x.u + 0x7FFFu + ((x.u >> 16) & 1u);
  return (unsigned short)(r >> 16);
}

// RNE pack of two f32 -> one u32 of 2 bf16 (correctness verified in R10)
__device__ __forceinline__ unsigned cvt_pk(float lo, float hi) {
  unsigned d;
  asm("v_cvt_pk_bf16_f32 %0, %1, %2" : "=v"(d) : "v"(lo), "v"(hi));
  return d;
}

__device__ __forceinline__ f32x4 mfma16(bf16x8 a, bf16x8 b, f32x4 c) {
  return __builtin_amdgcn_mfma_f32_16x16x32_bf16(a, b, c, 0, 0, 0);
}

__device__ __forceinline__ bf16x8 ones8() {
  bf16x8 v;
  for (int j = 0; j < 8; ++j) v[j] = (__bf16)1.0f;
  return v;
}

// ---------------------------------------------------------------------------
// Kernel 1: Wt[c][k] = W*(k, c%64) * (c<64 ? SCALE*log2e : 1), bf16.
// Q pre-scaled into the log2 domain: attn softmax uses raw exp2.
// ---------------------------------------------------------------------------
__global__ void prep_w(const float* __restrict__ Wq, const float* __restrict__ Wk,
                       const float* __restrict__ Wv, unsigned short* __restrict__ Wt) {
  int c = blockIdx.x;
  const float* W = (c < 64) ? Wq : (c < 128) ? Wk : Wv;
  int cc = c & 63;
  float sc = (c < 64) ? (SCALE * LOG2E) : 1.0f;
  for (int k = threadIdx.x; k < CDIM; k += blockDim.x)
    Wt[c * CDIM + k] = f2bf(W[k * NHEAD + cc] * sc);
}

// ---------------------------------------------------------------------------
// Kernel 2: fused QKV projection, BK=128 with register prefetch.
// M-tile = 32 rows, 512 blocks x 4 waves -> 2 blocks/CU.
// Writes q,k row-major [BT][64] bf16; v transposed [64][BT] bf16.
// ---------------------------------------------------------------------------
__global__ __launch_bounds__(256) void proj_qkv(
    const float* __restrict__ x, const unsigned short* __restrict__ Wt,
    unsigned short* __restrict__ qws, unsigned short* __restrict__ kws,
    unsigned short* __restrict__ vtws) {
  __shared__ unsigned short xlds[32][136];  // 128 bf16 + 8 pad
  const int tid = threadIdx.x;
  const int lane = tid & 63;
  const int w = tid >> 6;
  const int g = lane >> 4;
  const int c15 = lane & 15;
  const int rb = blockIdx.x * 32;

  f32x4 acc[2][3];
  for (int i = 0; i < 2; i++)
    for (int j = 0; j < 3; j++) acc[i][j] = (f32x4){0.f, 0.f, 0.f, 0.f};

  const int sr = tid >> 3;         // staging row 0..31
  const int scc = (tid & 7) * 16;  // staging col base (floats)
  const float* xrow = x + (size_t)(rb + sr) * CDIM + scc;

  float4 cur[4];
  for (int i = 0; i < 4; i++) cur[i] = *(const float4*)(xrow + i * 4);

  for (int k0 = 0; k0 < CDIM; k0 += 128) {
    unsigned short pk[16];
    for (int i = 0; i < 4; i++) {
      pk[i * 4 + 0] = f2bf(cur[i].x);
      pk[i * 4 + 1] = f2bf(cur[i].y);
      pk[i * 4 + 2] = f2bf(cur[i].z);
      pk[i * 4 + 3] = f2bf(cur[i].w);
    }
    *(bf16x8*)&xlds[sr][scc] = *(bf16x8*)&pk[0];
    *(bf16x8*)&xlds[sr][scc + 8] = *(bf16x8*)&pk[8];
    __syncthreads();
    if (k0 + 128 < CDIM)
      for (int i = 0; i < 4; i++)
        cur[i] = *(const float4*)(xrow + k0 + 128 + i * 4);

    for (int kk = 0; kk < 4; kk++) {
      bf16x8 a[2];
      for (int mt = 0; mt < 2; mt++)
        a[mt] = *(bf16x8*)&xlds[mt * 16 + c15][kk * 32 + g * 8];
      for (int bn = 0; bn < 3; bn++) {
        int col = w * 48 + bn * 16 + c15;
        bf16x8 bfrag =
            *(const bf16x8*)&Wt[(size_t)col * CDIM + k0 + kk * 32 + g * 8];
        for (int mt = 0; mt < 2; mt++)
          acc[mt][bn] = mfma16(a[mt], bfrag, acc[mt][bn]);
      }
    }
    __syncthreads();
  }

  for (int mt = 0; mt < 2; mt++)
    for (int bn = 0; bn < 3; bn++) {
      int col = w * 48 + bn * 16 + c15;
      int row0 = rb + mt * 16 + 4 * g;
      for (int r = 0; r < 4; r++) {
        unsigned short v = f2bf(acc[mt][bn][r]);
        int t = row0 + r;
        if (col < 64)
          qws[(size_t)t * 64 + col] = v;
        else if (col < 128)
          kws[(size_t)t * 64 + (col - 64)] = v;
        else
          vtws[(size_t)(col - 128) * BT + t] = v;
      }
    }
}

// ---------------------------------------------------------------------------
// Kernel 3: causal flash attention, VALU diet + no-spill launch shape.
// STRUCTURAL CONSTRAINT (verified R2/R7/R10): live state ~150 regs -> max
// 3 waves/SIMD; any config forcing a 128-reg cap ((512,4), 1024-thr blocks)
// spills to scratch (300+ MB traffic). So: 256 blocks x 8 waves,
// __launch_bounds__(512,2) (cap 256), in-block light/heavy q-tile halves
// (uniform 129 steps), ILP via ping-pong K/V prefetch instead of TLP.
// VALU diet vs R9 (~490 -> ~290 instr/step): cvt_pk 1-op packing, exp2
// domain (Q pre-scaled by SCALE*log2e), ping-pong (no rotate movs).
// S = mfma(K,Q): lane c = q-row, keys on 4g+r. l via ones-MFMA; defer-max
// THR2=11 (log2). P per-wave LDS, u64-only, PSTR=9 -> 0 conflicts (measured).
// Per-wave WREG 8960 B: P [32][9] u64 in loop; o[32][68] f32 @0, m @8704,
// l @8832 after.
// ---------------------------------------------------------------------------
__global__ __launch_bounds__(512, 2) void attn_fwd(
    const unsigned short* __restrict__ qws, const unsigned short* __restrict__ kws,
    const unsigned short* __restrict__ vtws, float* __restrict__ out) {
  __shared__ __align__(16) char smem[NW * WREG];  // 70 KiB
  const int tid = threadIdx.x;
  const int lane = tid & 63;
  const int w = tid >> 6;
  const int g = lane >> 4;
  const int c = lane & 15;
  const int b = blockIdx.x >> 6;
  const int pi = blockIdx.x & 63;
  const size_t rowbase = (size_t)b * T_SEQ;
  char* wbase = smem + w * WREG;
  u64* pl = (u64*)wbase;  // P tile: row stride PSTR u64
  const bf16x8 vone = ones8();

  for (int half = 0; half < 2; ++half) {
    const int qt = half ? (127 - pi) : pi;
    const int qb = qt * 32;
    const int nsteps = qt + 1;

    bf16x8 qf[2][2];
    for (int mi = 0; mi < 2; mi++)
      for (int hc = 0; hc < 2; hc++)
        qf[mi][hc] = *(const bf16x8*)&qws[(rowbase + qb + mi * 16 + c) * 64 +
                                          hc * 32 + g * 8];

    f32x4 o[2][4];
    f32x4 o5[2];
    float mrow[2];
    for (int mi = 0; mi < 2; mi++) {
      for (int nt = 0; nt < 4; nt++) o[mi][nt] = (f32x4){0.f, 0.f, 0.f, 0.f};
      o5[mi] = (f32x4){0.f, 0.f, 0.f, 0.f};
      mrow[mi] = -1e30f;
    }

    auto PREF = [&](int st, bf16x8 (&k0)[2], bf16x8 (&k1)[2], bf16x8 (&v)[4]) {
      const int kt = st * 32;
      for (int kn = 0; kn < 2; kn++) {
        k0[kn] = *(const bf16x8*)&kws[(rowbase + kt + kn * 16 + c) * 64 + g * 8];
        k1[kn] =
            *(const bf16x8*)&kws[(rowbase + kt + kn * 16 + c) * 64 + 32 + g * 8];
      }
      for (int nt = 0; nt < 4; nt++)
        v[nt] = *(const bf16x8*)&vtws[(size_t)(nt * 16 + c) * BT + rowbase + kt +
                                      g * 8];
    };

    auto COMPUTE = [&](int st, bf16x8 (&k0)[2], bf16x8 (&k1)[2], bf16x8 (&v)[4]) {
      const int kt = st * 32;
      f32x4 sv[2][2];
      for (int mi = 0; mi < 2; mi++)
        for (int kn = 0; kn < 2; kn++) {
          f32x4 z = (f32x4){0.f, 0.f, 0.f, 0.f};
          z = mfma16(k0[kn], qf[mi][0], z);
          sv[mi][kn] = mfma16(k1[kn], qf[mi][1], z);
        }

      if (st == nsteps - 1) {  // diagonal tile: causal mask
        for (int mi = 0; mi < 2; mi++)
          for (int kn = 0; kn < 2; kn++)
            for (int r = 0; r < 4; r++) {
              int key = kt + kn * 16 + 4 * g + r;
              int qr = qb + mi * 16 + c;
              if (key > qr) sv[mi][kn][r] = -1e30f;
            }
      }

      for (int mi = 0; mi < 2; mi++) {
        float t = fmaxf(
            fmaxf(fmaxf(sv[mi][0][0], sv[mi][0][1]),
                  fmaxf(sv[mi][0][2], sv[mi][0][3])),
            fmaxf(fmaxf(sv[mi][1][0], sv[mi][1][1]),
                  fmaxf(sv[mi][1][2], sv[mi][1][3])));
        t = fmaxf(t, __shfl_xor(t, 16));
        t = fmaxf(t, __shfl_xor(t, 32));
        if (__any(t > mrow[mi] + THR2)) {  // defer-max (log2 domain)
          float mn = fmaxf(mrow[mi], t);
          float a = exp2f(mrow[mi] - mn);
          mrow[mi] = mn;
          for (int nt = 0; nt < 4; nt++) o[mi][nt] *= a;
          o5[mi] *= a;
        }
        float p[8];
        for (int kn = 0; kn < 2; kn++)
          for (int r = 0; r < 4; r++)
            p[kn * 4 + r] = exp2f(sv[mi][kn][r] - mrow[mi]);
        unsigned d0 = cvt_pk(p[0], p[1]);
        unsigned d1 = cvt_pk(p[2], p[3]);
        unsigned d2 = cvt_pk(p[4], p[5]);
        unsigned d3 = cvt_pk(p[6], p[7]);
        int row = mi * 16 + c;
        pl[row * PSTR + g] = ((u64)d1 << 32) | d0;      // slots 0..3
        pl[row * PSTR + 4 + g] = ((u64)d3 << 32) | d2;  // slots 4..7
      }

      asm volatile("" ::: "memory");  // pin P stores before PV loads

      for (int mi = 0; mi < 2; mi++) {
        union { u64 q[2]; bf16x8 v8; } pu;
        pu.q[0] = pl[(mi * 16 + c) * PSTR + 2 * g];
        pu.q[1] = pl[(mi * 16 + c) * PSTR + 2 * g + 1];
        bf16x8 pa = pu.v8;
        for (int nt = 0; nt < 4; nt++)
          o[mi][nt] = mfma16(v[nt], pa, o[mi][nt]);
        o5[mi] = mfma16(vone, pa, o5[mi]);
      }
    };

    // ping-pong double buffer (no rotate movs)
    bf16x8 ka0[2], ka1[2], va[4], kb0[2], kb1[2], vb[4];
    if (w < nsteps) PREF(w, ka0, ka1, va);
    int st = w;
    while (st < nsteps) {
      if (st + NW < nsteps) PREF(st + NW, kb0, kb1, vb);
      COMPUTE(st, ka0, ka1, va);
      st += NW;
      if (st >= nsteps) break;
      if (st + NW < nsteps) PREF(st + NW, ka0, ka1, va);
      COMPUTE(st, kb0, kb1, vb);
      st += NW;
    }

    // ---- per-wave partials (P region dead now); o stride 68 f32 ----
    float* ow = (float*)wbase;
    float* mw = (float*)(wbase + 8704);
    float* lw = (float*)(wbase + 8832);
    for (int mi = 0; mi < 2; mi++)
      for (int nt = 0; nt < 4; nt++)
        for (int r = 0; r < 4; r++)
          ow[(mi * 16 + c) * 68 + nt * 16 + 4 * g + r] = o[mi][nt][r];
    if (g == 0)
      for (int mi = 0; mi < 2; mi++) {
        mw[mi * 16 + c] = mrow[mi];
        lw[mi * 16 + c] = o5[mi][0];
      }
    __syncthreads();

    // ---- LSE-merge across 8 waves (log2 domain): 512 thr x 4 = 32x64 ----
    for (int i = 0; i < 4; i++) {
      int e = tid + i * 512;
      int row = e >> 6;
      int d = e & 63;
      float M = -1e30f;
      for (int ww = 0; ww < NW; ww++)
        M = fmaxf(M, ((const float*)(smem + ww * WREG + 8704))[row]);
      float L = 0.f, O = 0.f;
      for (int ww = 0; ww < NW; ww++) {
        float mv = ((const float*)(smem + ww * WREG + 8704))[row];
        float f = exp2f(mv - M);
        L += f * ((const float*)(smem + ww * WREG + 8832))[row];
        O += f * ((const float*)(smem + ww * WREG))[row * 68 + d];
      }
      out[(rowbase + qb + row) * 64 + d] = O / L;
    }
    __syncthreads();  // merge reads done before next half reuses P region
  }
}

// ---------------------------------------------------------------------------
extern "C" void kernel_launch(void* const* d_in, const int* in_sizes, int n_in,
                              void* d_out, int out_size, void* d_ws, size_t ws_size,
                              hipStream_t stream) {
  const float* x = (const float*)d_in[0];
  const float* Wq = (const float*)d_in[1];
  const float* Wk = (const float*)d_in[2];
  const float* Wv = (const float*)d_in[3];
  float* out = (float*)d_out;

  char* ws = (char*)d_ws;
  unsigned short* Wt = (unsigned short*)(ws);                          // 384 KB
  unsigned short* qws = (unsigned short*)(ws + 393216);                // 2 MB
  unsigned short* kws = (unsigned short*)(ws + 393216 + 2097152);      // 2 MB
  unsigned short* vtws = (unsigned short*)(ws + 393216 + 2 * 2097152); // 2 MB

  prep_w<<<dim3(192), dim3(256), 0, stream>>>(Wq, Wk, Wv, Wt);
  proj_qkv<<<dim3(512), dim3(256), 0, stream>>>(x, Wt, qws, kws, vtws);
  attn_fwd<<<dim3(256), dim3(512), 0, stream>>>(qws, kws, vtws, out);
}

// Round 12
// 80.492 us; speedup vs baseline: 2.8755x; 1.0590x over previous
//
#include <hip/hip_runtime.h>

#define T_SEQ 4096
#define NBATCH 4
#define CDIM 1024
#define NHEAD 64
#define SCALE (1.0f / 32.0f)
#define LOG2E 1.4426950408889634f
#define BT (NBATCH * T_SEQ)
#define NW 8             // waves per attn block (key-split factor)
#define WREG 8960        // per-wave LDS region bytes
#define PSTR 17          // P-tile row stride in u64: 16 data slots + 1 pad
#define THR2 11.0f       // defer-max threshold in log2 domain (~8 nats)

typedef __bf16 bf16x8 __attribute__((ext_vector_type(8)));
typedef float f32x4 __attribute__((ext_vector_type(4)));
typedef unsigned long long u64;

__device__ __forceinline__ unsigned short f2bf(float f) {
  union { float f; unsigned u; } x;
  x.f = f;
  unsigned r = x.u + 0x7FFFu + ((x.u >> 16) & 1u);
  return (unsigned short)(r >> 16);
}

// RNE pack of two f32 -> one u32 of 2 bf16 (correctness verified R10/R11)
__device__ __forceinline__ unsigned cvt_pk(float lo, float hi) {
  unsigned d;
  asm("v_cvt_pk_bf16_f32 %0, %1, %2" : "=v"(d) : "v"(lo), "v"(hi));
  return d;
}

__device__ __forceinline__ f32x4 mfma16(bf16x8 a, bf16x8 b, f32x4 c) {
  return __builtin_amdgcn_mfma_f32_16x16x32_bf16(a, b, c, 0, 0, 0);
}

__device__ __forceinline__ bf16x8 ones8() {
  bf16x8 v;
  for (int j = 0; j < 8; ++j) v[j] = (__bf16)1.0f;
  return v;
}

// ---------------------------------------------------------------------------
// Kernel 1: Wt[c][k] = W*(k, c%64) * (c<64 ? SCALE*log2e : 1), bf16.
// ---------------------------------------------------------------------------
__global__ void prep_w(const float* __restrict__ Wq, const float* __restrict__ Wk,
                       const float* __restrict__ Wv, unsigned short* __restrict__ Wt) {
  int c = blockIdx.x;
  const float* W = (c < 64) ? Wq : (c < 128) ? Wk : Wv;
  int cc = c & 63;
  float sc = (c < 64) ? (SCALE * LOG2E) : 1.0f;
  for (int k = threadIdx.x; k < CDIM; k += blockDim.x)
    Wt[c * CDIM + k] = f2bf(W[k * NHEAD + cc] * sc);
}

// ---------------------------------------------------------------------------
// Kernel 2: fused QKV projection, BK=128 with register prefetch.
// M-tile = 32 rows, 512 blocks x 4 waves -> 2 blocks/CU.
// ---------------------------------------------------------------------------
__global__ __launch_bounds__(256) void proj_qkv(
    const float* __restrict__ x, const unsigned short* __restrict__ Wt,
    unsigned short* __restrict__ qws, unsigned short* __restrict__ kws,
    unsigned short* __restrict__ vtws) {
  __shared__ unsigned short xlds[32][136];  // 128 bf16 + 8 pad
  const int tid = threadIdx.x;
  const int lane = tid & 63;
  const int w = tid >> 6;
  const int g = lane >> 4;
  const int c15 = lane & 15;
  const int rb = blockIdx.x * 32;

  f32x4 acc[2][3];
  for (int i = 0; i < 2; i++)
    for (int j = 0; j < 3; j++) acc[i][j] = (f32x4){0.f, 0.f, 0.f, 0.f};

  const int sr = tid >> 3;         // staging row 0..31
  const int scc = (tid & 7) * 16;  // staging col base (floats)
  const float* xrow = x + (size_t)(rb + sr) * CDIM + scc;

  float4 cur[4];
  for (int i = 0; i < 4; i++) cur[i] = *(const float4*)(xrow + i * 4);

  for (int k0 = 0; k0 < CDIM; k0 += 128) {
    unsigned short pk[16];
    for (int i = 0; i < 4; i++) {
      pk[i * 4 + 0] = f2bf(cur[i].x);
      pk[i * 4 + 1] = f2bf(cur[i].y);
      pk[i * 4 + 2] = f2bf(cur[i].z);
      pk[i * 4 + 3] = f2bf(cur[i].w);
    }
    *(bf16x8*)&xlds[sr][scc] = *(bf16x8*)&pk[0];
    *(bf16x8*)&xlds[sr][scc + 8] = *(bf16x8*)&pk[8];
    __syncthreads();
    if (k0 + 128 < CDIM)
      for (int i = 0; i < 4; i++)
        cur[i] = *(const float4*)(xrow + k0 + 128 + i * 4);

    for (int kk = 0; kk < 4; kk++) {
      bf16x8 a[2];
      for (int mt = 0; mt < 2; mt++)
        a[mt] = *(bf16x8*)&xlds[mt * 16 + c15][kk * 32 + g * 8];
      for (int bn = 0; bn < 3; bn++) {
        int col = w * 48 + bn * 16 + c15;
        bf16x8 bfrag =
            *(const bf16x8*)&Wt[(size_t)col * CDIM + k0 + kk * 32 + g * 8];
        for (int mt = 0; mt < 2; mt++)
          acc[mt][bn] = mfma16(a[mt], bfrag, acc[mt][bn]);
      }
    }
    __syncthreads();
  }

  for (int mt = 0; mt < 2; mt++)
    for (int bn = 0; bn < 3; bn++) {
      int col = w * 48 + bn * 16 + c15;
      int row0 = rb + mt * 16 + 4 * g;
      for (int r = 0; r < 4; r++) {
        unsigned short v = f2bf(acc[mt][bn][r]);
        int t = row0 + r;
        if (col < 64)
          qws[(size_t)t * 64 + col] = v;
        else if (col < 128)
          kws[(size_t)t * 64 + (col - 64)] = v;
        else
          vtws[(size_t)(col - 128) * BT + t] = v;
      }
    }
}

// ---------------------------------------------------------------------------
// Kernel 3: causal flash attention, KVBLK=64 (fat steps).
// R11 diagnosis: per-step cost ~6400cy is dominated by FIXED overhead
// (serial shuffles, defer-max branch, P LDS round-trip, waitcnt drains) --
// accountable per-key work is ~5x smaller. So: 64 keys/step (4 K subtiles,
// 2 PV key-halves) halves step count; fixed costs amortize 2x. Per-key MFMA/
// pack/store counts unchanged. Loads at step top (R5 style; prefetch and
// ping-pong both measured neutral-to-negative, R9/R11).
// Shape: 256 blocks x 8 waves, launch_bounds(512,2) (cap 256; ~180 live regs,
// no spill; reg band 129-256 keeps 2 waves/SIMD -- same occupancy as R5).
// In-block light/heavy halves qt=pi, 127-pi: ~8-9 fat steps/wave uniform.
// S = mfma(K,Q), log2 domain (Q pre-scaled SCALE*log2e): lane c = q-row,
// key = kt + kn*16 + 4g+r. l via ones-MFMA; defer-max THR2=11.
// P tile per-wave LDS, u64-only + fence (R4 lesson), row = 64 keys = 16 u64
// slots, stride PSTR=17: store bank (2c+2g+8kn)%32 and load bank
// (2c+4g+16ks)%32 both uniform 4 lanes/bank-pair = b64 optimal floor.
// Per-wave WREG 8960 B: P [32][17] u64 (4352 B) in loop; o[32][68] f32 @0,
// m @8704, l @8832 after.
// ---------------------------------------------------------------------------
__global__ __launch_bounds__(512, 2) void attn_fwd(
    const unsigned short* __restrict__ qws, const unsigned short* __restrict__ kws,
    const unsigned short* __restrict__ vtws, float* __restrict__ out) {
  __shared__ __align__(16) char smem[NW * WREG];  // 70 KiB
  const int tid = threadIdx.x;
  const int lane = tid & 63;
  const int w = tid >> 6;
  const int g = lane >> 4;
  const int c = lane & 15;
  const int b = blockIdx.x >> 6;
  const int pi = blockIdx.x & 63;
  const size_t rowbase = (size_t)b * T_SEQ;
  char* wbase = smem + w * WREG;
  u64* pl = (u64*)wbase;  // P tile: row stride PSTR u64
  const bf16x8 vone = ones8();

  for (int half = 0; half < 2; ++half) {
    const int qt = half ? (127 - pi) : pi;
    const int qb = qt * 32;
    const int nsteps = (qb >> 6) + 1;  // 64-key steps covering keys 0..qb+31

    bf16x8 qf[2][2];
    for (int mi = 0; mi < 2; mi++)
      for (int hc = 0; hc < 2; hc++)
        qf[mi][hc] = *(const bf16x8*)&qws[(rowbase + qb + mi * 16 + c) * 64 +
                                          hc * 32 + g * 8];

    f32x4 o[2][4];
    f32x4 o5[2];
    float mrow[2];
    for (int mi = 0; mi < 2; mi++) {
      for (int nt = 0; nt < 4; nt++) o[mi][nt] = (f32x4){0.f, 0.f, 0.f, 0.f};
      o5[mi] = (f32x4){0.f, 0.f, 0.f, 0.f};
      mrow[mi] = -1e30f;
    }

    for (int st = w; st < nsteps; st += NW) {
      const int kt = st * 64;
      // K: 4 sub-tiles of 16 keys; V: 2 key-halves x 4 d-tiles
      bf16x8 kc0[4], kc1[4], vc[2][4];
      for (int kn = 0; kn < 4; kn++) {
        kc0[kn] = *(const bf16x8*)&kws[(rowbase + kt + kn * 16 + c) * 64 + g * 8];
        kc1[kn] =
            *(const bf16x8*)&kws[(rowbase + kt + kn * 16 + c) * 64 + 32 + g * 8];
      }
      for (int ks = 0; ks < 2; ks++)
        for (int nt = 0; nt < 4; nt++)
          vc[ks][nt] = *(const bf16x8*)&vtws[(size_t)(nt * 16 + c) * BT + rowbase +
                                             kt + ks * 32 + g * 8];

      // S = mfma(K, Q): lane c = q-row, key = kt + kn*16 + 4g+r (log2 units)
      f32x4 sv[2][4];
      for (int mi = 0; mi < 2; mi++)
        for (int kn = 0; kn < 4; kn++) {
          f32x4 z = (f32x4){0.f, 0.f, 0.f, 0.f};
          z = mfma16(kc0[kn], qf[mi][0], z);
          sv[mi][kn] = mfma16(kc1[kn], qf[mi][1], z);
        }

      if (st == nsteps - 1) {  // diagonal tile: causal mask
        for (int mi = 0; mi < 2; mi++)
          for (int kn = 0; kn < 4; kn++)
            for (int r = 0; r < 4; r++) {
              int key = kt + kn * 16 + 4 * g + r;
              int qr = qb + mi * 16 + c;
              if (key > qr) sv[mi][kn][r] = -1e30f;
            }
      }

      for (int mi = 0; mi < 2; mi++) {
        float t0 = fmaxf(fmaxf(sv[mi][0][0], sv[mi][0][1]),
                         fmaxf(sv[mi][0][2], sv[mi][0][3]));
        float t1 = fmaxf(fmaxf(sv[mi][1][0], sv[mi][1][1]),
                         fmaxf(sv[mi][1][2], sv[mi][1][3]));
        float t2 = fmaxf(fmaxf(sv[mi][2][0], sv[mi][2][1]),
                         fmaxf(sv[mi][2][2], sv[mi][2][3]));
        float t3 = fmaxf(fmaxf(sv[mi][3][0], sv[mi][3][1]),
                         fmaxf(sv[mi][3][2], sv[mi][3][3]));
        float t = fmaxf(fmaxf(t0, t1), fmaxf(t2, t3));
        t = fmaxf(t, __shfl_xor(t, 16));
        t = fmaxf(t, __shfl_xor(t, 32));
        if (__any(t > mrow[mi] + THR2)) {  // defer-max (log2 domain)
          float mn = fmaxf(mrow[mi], t);
          float a = exp2f(mrow[mi] - mn);
          mrow[mi] = mn;
          for (int nt = 0; nt < 4; nt++) o[mi][nt] *= a;
          o5[mi] *= a;
        }
        int row = mi * 16 + c;
        for (int kn = 0; kn < 4; kn++) {
          float p0 = exp2f(sv[mi][kn][0] - mrow[mi]);
          float p1 = exp2f(sv[mi][kn][1] - mrow[mi]);
          float p2 = exp2f(sv[mi][kn][2] - mrow[mi]);
          float p3 = exp2f(sv[mi][kn][3] - mrow[mi]);
          unsigned dlo = cvt_pk(p0, p1);
          unsigned dhi = cvt_pk(p2, p3);
          // keys kn*16+4g..+3 -> u64 slot kn*4+g
          pl[row * PSTR + kn * 4 + g] = ((u64)dhi << 32) | dlo;
        }
      }

      asm volatile("" ::: "memory");  // pin P stores before PV loads

      // PV: O = sum_ks mfma(V[ks], P[ks]); l = mfma(1, P[ks]).
      for (int mi = 0; mi < 2; mi++) {
        int row = mi * 16 + c;
        for (int ks = 0; ks < 2; ks++) {
          union { u64 q[2]; bf16x8 v8; } pu;
          pu.q[0] = pl[row * PSTR + ks * 8 + 2 * g];      // keys ks*32+8g..+3
          pu.q[1] = pl[row * PSTR + ks * 8 + 2 * g + 1];  // keys ks*32+8g+4..+7
          bf16x8 pa = pu.v8;
          for (int nt = 0; nt < 4; nt++)
            o[mi][nt] = mfma16(vc[ks][nt], pa, o[mi][nt]);
          o5[mi] = mfma16(vone, pa, o5[mi]);
        }
      }
    }

    // ---- per-wave partials (P region dead now); o stride 68 f32 ----
    float* ow = (float*)wbase;
    float* mw = (float*)(wbase + 8704);
    float* lw = (float*)(wbase + 8832);
    for (int mi = 0; mi < 2; mi++)
      for (int nt = 0; nt < 4; nt++)
        for (int r = 0; r < 4; r++)
          ow[(mi * 16 + c) * 68 + nt * 16 + 4 * g + r] = o[mi][nt][r];
    if (g == 0)
      for (int mi = 0; mi < 2; mi++) {
        mw[mi * 16 + c] = mrow[mi];
        lw[mi * 16 + c] = o5[mi][0];
      }
    __syncthreads();

    // ---- LSE-merge across 8 waves (log2 domain): 512 thr x 4 = 32x64 ----
    for (int i = 0; i < 4; i++) {
      int e = tid + i * 512;
      int row = e >> 6;
      int d = e & 63;
      float M = -1e30f;
      for (int ww = 0; ww < NW; ww++)
        M = fmaxf(M, ((const float*)(smem + ww * WREG + 8704))[row]);
      float L = 0.f, O = 0.f;
      for (int ww = 0; ww < NW; ww++) {
        float mv = ((const float*)(smem + ww * WREG + 8704))[row];
        float f = exp2f(mv - M);
        L += f * ((const float*)(smem + ww * WREG + 8832))[row];
        O += f * ((const float*)(smem + ww * WREG))[row * 68 + d];
      }
      out[(rowbase + qb + row) * 64 + d] = O / L;
    }
    __syncthreads();  // merge reads done before next half reuses P region
  }
}

// ---------------------------------------------------------------------------
extern "C" void kernel_launch(void* const* d_in, const int* in_sizes, int n_in,
                              void* d_out, int out_size, void* d_ws, size_t ws_size,
                              hipStream_t stream) {
  const float* x = (const float*)d_in[0];
  const float* Wq = (const float*)d_in[1];
  const float* Wk = (const float*)d_in[2];
  const float* Wv = (const float*)d_in[3];
  float* out = (float*)d_out;

  char* ws = (char*)d_ws;
  unsigned short* Wt = (unsigned short*)(ws);                          // 384 KB
  unsigned short* qws = (unsigned short*)(ws + 393216);                // 2 MB
  unsigned short* kws = (unsigned short*)(ws + 393216 + 2097152);      // 2 MB
  unsigned short* vtws = (unsigned short*)(ws + 393216 + 2 * 2097152); // 2 MB

  prep_w<<<dim3(192), dim3(256), 0, stream>>>(Wq, Wk, Wv, Wt);
  proj_qkv<<<dim3(512), dim3(256), 0, stream>>>(x, Wt, qws, kws, vtws);
  attn_fwd<<<dim3(256), dim3(512), 0, stream>>>(qws, kws, vtws, out);
}

// Round 13
// 79.652 us; speedup vs baseline: 2.9058x; 1.0106x over previous
//
#include <hip/hip_runtime.h>

#define T_SEQ 4096
#define NBATCH 4
#define CDIM 1024
#define NHEAD 64
#define SCALE (1.0f / 32.0f)
#define LOG2E 1.4426950408889634f
#define BT (NBATCH * T_SEQ)
#define NW 8             // waves per attn block (key-split factor)
#define WREG 8960        // per-wave LDS region bytes: o[32][68] f32 + m + l
#define THR2 11.0f       // defer-max threshold in log2 domain (~8 nats)

typedef __bf16 bf16x8 __attribute__((ext_vector_type(8)));
typedef float f32x4 __attribute__((ext_vector_type(4)));
typedef float f32x16 __attribute__((ext_vector_type(16)));
typedef unsigned long long u64;

__device__ __forceinline__ unsigned short f2bf(float f) {
  union { float f; unsigned u; } x;
  x.f = f;
  unsigned r = x.u + 0x7FFFu + ((x.u >> 16) & 1u);
  return (unsigned short)(r >> 16);
}

// RNE pack of two f32 -> one u32 of 2 bf16 (correctness verified R10-R12)
__device__ __forceinline__ unsigned cvt_pk(float lo, float hi) {
  unsigned d;
  asm("v_cvt_pk_bf16_f32 %0, %1, %2" : "=v"(d) : "v"(lo), "v"(hi));
  return d;
}

__device__ __forceinline__ f32x4 mfma16(bf16x8 a, bf16x8 b, f32x4 c) {
  return __builtin_amdgcn_mfma_f32_16x16x32_bf16(a, b, c, 0, 0, 0);
}

__device__ __forceinline__ f32x16 mfma32(bf16x8 a, bf16x8 b, f32x16 c) {
  return __builtin_amdgcn_mfma_f32_32x32x16_bf16(a, b, c, 0, 0, 0);
}

// ---------------------------------------------------------------------------
// Kernel 1: Wt[c][k] = W*(k, c%64) * (c<64 ? SCALE*log2e : 1), bf16.
// ---------------------------------------------------------------------------
__global__ void prep_w(const float* __restrict__ Wq, const float* __restrict__ Wk,
                       const float* __restrict__ Wv, unsigned short* __restrict__ Wt) {
  int c = blockIdx.x;
  const float* W = (c < 64) ? Wq : (c < 128) ? Wk : Wv;
  int cc = c & 63;
  float sc = (c < 64) ? (SCALE * LOG2E) : 1.0f;
  for (int k = threadIdx.x; k < CDIM; k += blockDim.x)
    Wt[c * CDIM + k] = f2bf(W[k * NHEAD + cc] * sc);
}

// ---------------------------------------------------------------------------
// Kernel 2: fused QKV projection. Change this round: ALL 12 Wt B-fragment
// loads per k0-step hoisted out of the kk-loop (R12 had them serialized
// per-kk -> 4 sequential ~200cy L2 latencies per step; now 12 in flight).
// M-tile = 32 rows, 512 blocks x 4 waves -> 2 blocks/CU.
// ---------------------------------------------------------------------------
__global__ __launch_bounds__(256) void proj_qkv(
    const float* __restrict__ x, const unsigned short* __restrict__ Wt,
    unsigned short* __restrict__ qws, unsigned short* __restrict__ kws,
    unsigned short* __restrict__ vtws) {
  __shared__ unsigned short xlds[32][136];  // 128 bf16 + 8 pad
  const int tid = threadIdx.x;
  const int lane = tid & 63;
  const int w = tid >> 6;
  const int g = lane >> 4;
  const int c15 = lane & 15;
  const int rb = blockIdx.x * 32;

  f32x4 acc[2][3];
  for (int i = 0; i < 2; i++)
    for (int j = 0; j < 3; j++) acc[i][j] = (f32x4){0.f, 0.f, 0.f, 0.f};

  const int sr = tid >> 3;         // staging row 0..31
  const int scc = (tid & 7) * 16;  // staging col base (floats)
  const float* xrow = x + (size_t)(rb + sr) * CDIM + scc;

  float4 cur[4];
  for (int i = 0; i < 4; i++) cur[i] = *(const float4*)(xrow + i * 4);

  for (int k0 = 0; k0 < CDIM; k0 += 128) {
    unsigned short pk[16];
    for (int i = 0; i < 4; i++) {
      pk[i * 4 + 0] = f2bf(cur[i].x);
      pk[i * 4 + 1] = f2bf(cur[i].y);
      pk[i * 4 + 2] = f2bf(cur[i].z);
      pk[i * 4 + 3] = f2bf(cur[i].w);
    }
    *(bf16x8*)&xlds[sr][scc] = *(bf16x8*)&pk[0];
    *(bf16x8*)&xlds[sr][scc + 8] = *(bf16x8*)&pk[8];
    __syncthreads();
    if (k0 + 128 < CDIM)
      for (int i = 0; i < 4; i++)
        cur[i] = *(const float4*)(xrow + k0 + 128 + i * 4);

    // hoisted: 12 independent Wt loads in flight at once
    bf16x8 wfrag[4][3];
    for (int kk = 0; kk < 4; kk++)
      for (int bn = 0; bn < 3; bn++) {
        int col = w * 48 + bn * 16 + c15;
        wfrag[kk][bn] =
            *(const bf16x8*)&Wt[(size_t)col * CDIM + k0 + kk * 32 + g * 8];
      }

    for (int kk = 0; kk < 4; kk++) {
      bf16x8 a[2];
      for (int mt = 0; mt < 2; mt++)
        a[mt] = *(bf16x8*)&xlds[mt * 16 + c15][kk * 32 + g * 8];
      for (int bn = 0; bn < 3; bn++)
        for (int mt = 0; mt < 2; mt++)
          acc[mt][bn] = mfma16(a[mt], wfrag[kk][bn], acc[mt][bn]);
    }
    __syncthreads();
  }

  for (int mt = 0; mt < 2; mt++)
    for (int bn = 0; bn < 3; bn++) {
      int col = w * 48 + bn * 16 + c15;
      int row0 = rb + mt * 16 + 4 * g;
      for (int r = 0; r < 4; r++) {
        unsigned short v = f2bf(acc[mt][bn][r]);
        int t = row0 + r;
        if (col < 64)
          qws[(size_t)t * 64 + col] = v;
        else if (col < 128)
          kws[(size_t)t * 64 + (col - 64)] = v;
        else
          vtws[(size_t)(col - 128) * BT + t] = v;
      }
    }
}

// ---------------------------------------------------------------------------
// Kernel 3: causal flash attention on 32x32x16 MFMA, register-resident P.
// R12 lesson: per-key cost constant across step sizes; serial chain through
// {2x 16-lane shuffle, LDS P store->fence->drain->load} dominates. New
// structure eliminates both:
//   S = mfma32(K,Q): lane l holds 16 S-vals of q-row (l&31); lanes l and
//   l^32 jointly hold the row (key sets A/B interleaved by 4).
//   Row max/sum: in-lane tree + ONE __shfl_xor(.,32).
//   P -> PV B-frag: 8 cvt_pk + 8 __shfl_xor(.,32) + 8 cndmask, all in regs.
//   PV: O = mfma32(V, P~) over 2 key-halves x 2 d-tiles. l by VALU sum.
// D-layout 32x32 (HW-verified m74/m101): col=lane&31, row=(r&3)+8*(r>>2)
// +4*(lane>>5). A/B: row(col)=lane&31, k=(lane>>5)*8+j.
// 256 blocks x 8 waves, launch_bounds(512,2) (~150 live regs, no spill);
// block does qt=pi then 127-pi; wave w: st=w,w+8,... 32 keys/step.
// Per-wave WREG 8960 B (epilogue only): o[32][68] f32 @0, m @8704, l @8832.
// ---------------------------------------------------------------------------
__global__ __launch_bounds__(512, 2) void attn_fwd(
    const unsigned short* __restrict__ qws, const unsigned short* __restrict__ kws,
    const unsigned short* __restrict__ vtws, float* __restrict__ out) {
  __shared__ __align__(16) char smem[NW * WREG];  // 70 KiB
  const int tid = threadIdx.x;
  const int lane = tid & 63;
  const int w = tid >> 6;
  const int q31 = lane & 31;   // q-row within tile
  const int hi = lane >> 5;    // key-set selector (A/B)
  const int b = blockIdx.x >> 6;
  const int pi = blockIdx.x & 63;
  const size_t rowbase = (size_t)b * T_SEQ;
  char* wbase = smem + w * WREG;

  for (int half = 0; half < 2; ++half) {
    const int qt = half ? (127 - pi) : pi;
    const int qb = qt * 32;
    const int nsteps = qt + 1;  // 32-key steps

    // Q B-frag: col=q31, k = hi2*16 + hi*8 + j
    bf16x8 qf[4];
    for (int h2 = 0; h2 < 4; h2++)
      qf[h2] = *(const bf16x8*)&qws[(rowbase + qb + q31) * 64 + h2 * 16 + hi * 8];

    f32x16 o[2];
    o[0] = (f32x16)0.f;
    o[1] = (f32x16)0.f;
    float mrow = -1e30f;
    float lrun = 0.f;

    for (int st = w; st < nsteps; st += NW) {
      const int kt = st * 32;
      // K A-frag: row = key q31, k = h2*16 + hi*8 + j
      bf16x8 ka[4];
      for (int h2 = 0; h2 < 4; h2++)
        ka[h2] =
            *(const bf16x8*)&kws[(rowbase + kt + q31) * 64 + h2 * 16 + hi * 8];
      // V A-frag: row = d (nt*32 + q31), k = keys ki*16 + hi*8 + j
      bf16x8 va[2][2];
      for (int nt = 0; nt < 2; nt++)
        for (int ki = 0; ki < 2; ki++)
          va[nt][ki] = *(const bf16x8*)&vtws[(size_t)(nt * 32 + q31) * BT +
                                             rowbase + kt + ki * 16 + hi * 8];

      // S = mfma32(K, Q): lane holds S[q=q31][key = kt + (r&3)+8*(r>>2)+4*hi]
      f32x16 s = (f32x16)0.f;
      for (int h2 = 0; h2 < 4; h2++) s = mfma32(ka[h2], qf[h2], s);

      float sv[16];
      for (int r = 0; r < 16; r++) sv[r] = s[r];

      if (st == nsteps - 1) {  // diagonal tile: causal mask
        for (int r = 0; r < 16; r++) {
          int key = kt + (r & 3) + 8 * (r >> 2) + 4 * hi;
          if (key > qb + q31) sv[r] = -1e30f;
        }
      }

      // row max: in-lane tree + one xor32
      float t01 = fmaxf(sv[0], sv[1]), t23 = fmaxf(sv[2], sv[3]);
      float t45 = fmaxf(sv[4], sv[5]), t67 = fmaxf(sv[6], sv[7]);
      float t89 = fmaxf(sv[8], sv[9]), tab = fmaxf(sv[10], sv[11]);
      float tcd = fmaxf(sv[12], sv[13]), tef = fmaxf(sv[14], sv[15]);
      float t = fmaxf(fmaxf(fmaxf(t01, t23), fmaxf(t45, t67)),
                      fmaxf(fmaxf(t89, tab), fmaxf(tcd, tef)));
      t = fmaxf(t, __shfl_xor(t, 32));
      if (__any(t > mrow + THR2)) {  // defer-max (log2 domain)
        float mn = fmaxf(mrow, t);
        float a = exp2f(mrow - mn);
        mrow = mn;
        o[0] *= a;
        o[1] *= a;
        lrun *= a;
      }
      float p[16];
      for (int r = 0; r < 16; r++) p[r] = exp2f(sv[r] - mrow);

      // l: in-lane sum + xor32
      float ssum = 0.f;
      for (int r = 0; r < 16; r++) ssum += p[r];
      lrun += ssum + __shfl_xor(ssum, 32);

      // pack + swap halves: X[j]=(p[2j],p[2j+1]); Y[j]=partner X[j]
      unsigned X[8], Y[8];
      for (int j = 0; j < 8; j++) X[j] = cvt_pk(p[2 * j], p[2 * j + 1]);
      for (int j = 0; j < 8; j++) Y[j] = __shfl_xor(X[j], 32);

      // PV B-frags (keys ki*16..+15): lane provides keys ki*16+hi*8..+7
      union { unsigned u[4]; bf16x8 v; } bf0, bf1;
      bf0.u[0] = hi ? Y[2] : X[0];
      bf0.u[1] = hi ? Y[3] : X[1];
      bf0.u[2] = hi ? X[2] : Y[0];
      bf0.u[3] = hi ? X[3] : Y[1];
      bf1.u[0] = hi ? Y[6] : X[4];
      bf1.u[1] = hi ? Y[7] : X[5];
      bf1.u[2] = hi ? X[6] : Y[4];
      bf1.u[3] = hi ? X[7] : Y[5];

      for (int nt = 0; nt < 2; nt++) {
        o[nt] = mfma32(va[nt][0], bf0.v, o[nt]);
        o[nt] = mfma32(va[nt][1], bf1.v, o[nt]);
      }
    }

    // ---- per-wave partials; o stride 68 f32 ----
    float* ow = (float*)wbase;
    float* mw = (float*)(wbase + 8704);
    float* lw = (float*)(wbase + 8832);
    for (int nt = 0; nt < 2; nt++)
      for (int r = 0; r < 16; r++) {
        int d = nt * 32 + (r & 3) + 8 * (r >> 2) + 4 * hi;
        ow[q31 * 68 + d] = o[nt][r];
      }
    if (hi == 0) {
      mw[q31] = mrow;
      lw[q31] = lrun;
    }
    __syncthreads();

    // ---- LSE-merge across 8 waves (log2 domain): 512 thr x 4 = 32x64 ----
    for (int i = 0; i < 4; i++) {
      int e = tid + i * 512;
      int row = e >> 6;
      int d = e & 63;
      float M = -1e30f;
      for (int ww = 0; ww < NW; ww++)
        M = fmaxf(M, ((const float*)(smem + ww * WREG + 8704))[row]);
      float L = 0.f, O = 0.f;
      for (int ww = 0; ww < NW; ww++) {
        float mv = ((const float*)(smem + ww * WREG + 8704))[row];
        float f = exp2f(mv - M);
        L += f * ((const float*)(smem + ww * WREG + 8832))[row];
        O += f * ((const float*)(smem + ww * WREG))[row * 68 + d];
      }
      out[(rowbase + qb + row) * 64 + d] = O / L;
    }
    __syncthreads();  // merge reads done before next half reuses partials
  }
}

// ---------------------------------------------------------------------------
extern "C" void kernel_launch(void* const* d_in, const int* in_sizes, int n_in,
                              void* d_out, int out_size, void* d_ws, size_t ws_size,
                              hipStream_t stream) {
  const float* x = (const float*)d_in[0];
  const float* Wq = (const float*)d_in[1];
  const float* Wk = (const float*)d_in[2];
  const float* Wv = (const float*)d_in[3];
  float* out = (float*)d_out;

  char* ws = (char*)d_ws;
  unsigned short* Wt = (unsigned short*)(ws);                          // 384 KB
  unsigned short* qws = (unsigned short*)(ws + 393216);                // 2 MB
  unsigned short* kws = (unsigned short*)(ws + 393216 + 2097152);      // 2 MB
  unsigned short* vtws = (unsigned short*)(ws + 393216 + 2 * 2097152); // 2 MB

  prep_w<<<dim3(192), dim3(256), 0, stream>>>(Wq, Wk, Wv, Wt);
  proj_qkv<<<dim3(512), dim3(256), 0, stream>>>(x, Wt, qws, kws, vtws);
  attn_fwd<<<dim3(256), dim3(512), 0, stream>>>(qws, kws, vtws, out);
}